// Round 9
// baseline (1191.959 us; speedup 1.0000x reference)
//
#include <hip/hip_runtime.h>
#include <hip/hip_fp16.h>

#define T_SEQ   2048
#define HID     50
#define NPAD    256     // type-major: n = type*64 + u  (u<50 real, 4 gate types)
#define KPAD    64      // 50 h + 13 onehot + 1 bias
#define MB      8       // batch rows per block
#define NBLK    256     // 2048 / MB -> 1 block/CU
#define NTHR    256     // 4 waves
#define HSTR    80      // hA row stride in ushorts (160B, 16B-aligned, bank-friendly)

typedef __attribute__((ext_vector_type(8))) _Float16 half8;
typedef __attribute__((ext_vector_type(4))) float    f32x4;

__device__ __forceinline__ ushort f16b(float f) {
    return __half_as_ushort(__float2half(f));   // RNE
}
__device__ __forceinline__ float rcp_(float x) { return __builtin_amdgcn_rcpf(x); }
__device__ __forceinline__ float sigm(float x) { return rcp_(1.f + __expf(-x)); }
__device__ __forceinline__ float tanh_(float x) {
    return fmaf(2.f, rcp_(1.f + __expf(-2.f * x)), -1.f);
}

// B[n][k] f16 bits, n = type*64 + u (type 0..3 = i,f,g,o; u<50 real, else 0):
//  k in [0,50) : W_hh[g][k], g = type*50+u
//  k in [50,63): Ttab[v=k-50][g]   (x onehot)
//  k == 63     : b_ih[g]+b_hh[g]   (x 1)
__global__ void build_B(const float* __restrict__ embed,
                        const float* __restrict__ Wih,
                        const float* __restrict__ Whh,
                        const float* __restrict__ bih,
                        const float* __restrict__ bhh,
                        ushort* __restrict__ B) {
    int idx = blockIdx.x * blockDim.x + threadIdx.x;
    if (idx >= NPAD * KPAD) return;
    int n = idx >> 6, k = idx & 63;
    int type = n >> 6, u = n & 63;
    ushort v = 0;
    if (u < HID) {
        int g = type * HID + u;
        if (k < HID) {
            v = f16b(Whh[g * HID + k]);
        } else if (k < 63) {
            int vv = k - HID;
            float tt = 0.f;
            for (int e = 0; e < HID; ++e)
                tt = fmaf(embed[vv * HID + e], Wih[g * HID + e], tt);
            v = f16b(tt);
        } else {
            v = f16b(bih[g] + bhh[g]);
        }
    }
    B[idx] = v;
}

// 256 blocks x 256 threads (4 waves); block = batch rows [blockIdx.x*8, +8).
// In-register activation: wave w owns u-group w; i/f/g/o for (u, rows q*4+r)
// land in the SAME lane's 4 C-fragments. c-state in registers. hA double-
// buffered -> ONE barrier per step, no G matrix in LDS at all.
__global__ __launch_bounds__(NTHR, 1) void lstm_mfma(
    const int*    __restrict__ x,
    const ushort* __restrict__ Bmat,
    const float*  __restrict__ W1,
    const float*  __restrict__ b1,
    const float*  __restrict__ W2,
    const float*  __restrict__ b2,
    float*        __restrict__ out)
{
    const int t   = threadIdx.x;
    const int w   = t >> 6;
    const int l   = t & 63;
    const int c16 = l & 15;
    const int q   = l >> 4;

    __shared__ __align__(16) ushort hA[2][MB * HSTR];   // ping-pong A staging
    __shared__ float R1[MB][HID + 2];                   // epilogue scratch

    // wave w: tiles {w, 4+w, 8+w, 12+w} = types 0..3 of u in [16w, 16w+16)
    half8 bf[4][2];
    #pragma unroll
    for (int ty = 0; ty < 4; ++ty)
        #pragma unroll
        for (int kf = 0; kf < 2; ++kf)
            bf[ty][kf] = *(const half8*)(Bmat + (ty * 64 + w * 16 + c16) * KPAD
                                               + kf * 32 + q * 8);
    #pragma unroll
    for (int ty = 0; ty < 4; ++ty)
        #pragma unroll
        for (int kf = 0; kf < 2; ++kf)
            asm volatile("" : "+v"(bf[ty][kf]));

    for (int i = t; i < 2 * MB * HSTR; i += NTHR) ((ushort*)hA)[i] = 0;
    __syncthreads();

    const long xbase = (long)blockIdx.x * MB * T_SEQ;
    int tm1 = 0, t0 = 0, tp1 = 0;    // x[s-1], x[s], x[s+1] (t<MB lanes)
    if (t < MB) {
        int k0 = x[xbase + (long)t * T_SEQ + 0];
        int k1 = x[xbase + (long)t * T_SEQ + 1];
        hA[0][t * HSTR + 63] = 0x3C00;          // bias slot = 1.0 (both bufs)
        hA[1][t * HSTR + 63] = 0x3C00;
        hA[0][t * HSTR + HID + k0] = 0x3C00;    // onehot for step 0
        tm1 = k0; t0 = k0; tp1 = k1;            // clearing k0 in zeroed buf1 is a no-op
    }
    float c[4] = {0.f, 0.f, 0.f, 0.f};          // cell state rows q*4+r (q<2)
    __syncthreads();

    const int rsel = (c16 & 7) * HSTR + q * 8;  // A rows 8..15 wrap onto 0..7
    const int u    = w * 16 + c16;              // this lane's hidden unit

    for (int s = 0; s < T_SEQ; ++s) {
        const ushort* rb = hA[s & 1];
        ushort*       wb = hA[(s + 1) & 1];

        half8 a0 = *(const half8*)(rb + rsel);
        half8 a1 = *(const half8*)(rb + rsel + 32);

        f32x4 zi = {0.f,0.f,0.f,0.f}, zf = {0.f,0.f,0.f,0.f};
        f32x4 zg = {0.f,0.f,0.f,0.f}, zo = {0.f,0.f,0.f,0.f};
        zi = __builtin_amdgcn_mfma_f32_16x16x32_f16(a0, bf[0][0], zi, 0, 0, 0);
        zf = __builtin_amdgcn_mfma_f32_16x16x32_f16(a0, bf[1][0], zf, 0, 0, 0);
        zg = __builtin_amdgcn_mfma_f32_16x16x32_f16(a0, bf[2][0], zg, 0, 0, 0);
        zo = __builtin_amdgcn_mfma_f32_16x16x32_f16(a0, bf[3][0], zo, 0, 0, 0);
        zi = __builtin_amdgcn_mfma_f32_16x16x32_f16(a1, bf[0][1], zi, 0, 0, 0);
        zf = __builtin_amdgcn_mfma_f32_16x16x32_f16(a1, bf[1][1], zf, 0, 0, 0);
        zg = __builtin_amdgcn_mfma_f32_16x16x32_f16(a1, bf[2][1], zg, 0, 0, 0);
        zo = __builtin_amdgcn_mfma_f32_16x16x32_f16(a1, bf[3][1], zo, 0, 0, 0);

        if (q < 2) {   // rows q*4+r = 0..7 real; activation fully lane-local
            #pragma unroll
            for (int r = 0; r < 4; ++r) {
                float iv = sigm(zi[r]);
                float fv = sigm(zf[r]);
                float gv = tanh_(zg[r]);
                float ov = sigm(zo[r]);
                c[r] = fv * c[r] + iv * gv;
                float h = ov * tanh_(c[r]);
                if (u < HID)
                    wb[(q * 4 + r) * HSTR + u] = f16b(h);
            }
        }
        if (t < MB) {
            wb[t * HSTR + HID + tm1] = 0;                   // clear onehot(x[s-1])
            if (s + 1 < T_SEQ) wb[t * HSTR + HID + tp1] = 0x3C00; // set x[s+1]
            tm1 = t0; t0 = tp1;
            if (s + 2 < T_SEQ) tp1 = x[xbase + (long)t * T_SEQ + s + 2];
        }
        __syncthreads();   // single barrier: wb complete before it becomes rb
    }

    // Epilogue MLP: final h is in hA[0] (T_SEQ even)
    const ushort* hf = hA[0];
    if (t < 4 * HID) {                 // 200 threads, each does 2 rows
        int uu = t % HID;
        int mb = t / HID;
        #pragma unroll
        for (int hlf = 0; hlf < 2; ++hlf) {
            int m = mb + 4 * hlf;
            float a = b1[uu];
            #pragma unroll 10
            for (int k = 0; k < HID; ++k)
                a = fmaf(W1[uu * HID + k],
                         __half2float(__ushort_as_half(hf[m * HSTR + k])), a);
            R1[m][uu] = fmaxf(a, 0.f);
        }
    }
    __syncthreads();
    if (t < MB) {
        float a = b2[0];
        #pragma unroll 10
        for (int j = 0; j < HID; ++j)
            a = fmaf(W2[j], R1[t][j], a);
        out[blockIdx.x * MB + t] = a;
    }
}

extern "C" void kernel_launch(void* const* d_in, const int* in_sizes, int n_in,
                              void* d_out, int out_size, void* d_ws, size_t ws_size,
                              hipStream_t stream) {
    const int*   x     = (const int*)  d_in[0];
    const float* embed = (const float*)d_in[1];
    const float* W_ih  = (const float*)d_in[2];
    const float* W_hh  = (const float*)d_in[3];
    const float* b_ih  = (const float*)d_in[4];
    const float* b_hh  = (const float*)d_in[5];
    const float* W1    = (const float*)d_in[6];
    const float* b1    = (const float*)d_in[7];
    const float* W2    = (const float*)d_in[8];
    const float* b2    = (const float*)d_in[9];
    float* out = (float*)d_out;

    ushort* Bmat = (ushort*)d_ws;  // NPAD*KPAD*2 = 32,768 B scratch

    build_B<<<(NPAD * KPAD + 255) / 256, 256, 0, stream>>>(
        embed, W_ih, W_hh, b_ih, b_hh, Bmat);

    lstm_mfma<<<NBLK, NTHR, 0, stream>>>(
        x, Bmat, W1, b1, W2, b2, out);
}